// Round 1
// baseline (216.862 us; speedup 1.0000x reference)
//
#include <hip/hip_runtime.h>

// LinearAutoDecoder: per-row sparse 3-channel projection.
// rgb[n, j] = dot(X[n, :63],  W_pos[3*cid[n]+j, :]) +
//             dot(X[n, 63:], W_feat[3*cid[n]+j, :])
//
// One wave (64 lanes) per row. X reads coalesced (lane = feature index mod 64).
// Weight reads are wave-uniform-base + lane offset -> coalesced, L2-resident
// (total weights = 245 KB << 4 MiB per-XCD L2).

constexpr int POS = 63;
constexpr int LAT = 256;
constexpr int DIM = POS + LAT;  // 319

__global__ __launch_bounds__(256) void lad_kernel(
    const float* __restrict__ X,
    const int*   __restrict__ cid,
    const float* __restrict__ Wp,   // [192, 63]
    const float* __restrict__ Wf,   // [192, 256]
    float*       __restrict__ out,  // [N, 3]
    int n)
{
    const int lane = threadIdx.x & 63;
    const int wave = (int)((blockIdx.x * blockDim.x + threadIdx.x) >> 6);
    if (wave >= n) return;

    const size_t row = (size_t)wave;
    const float* xrow = X + row * (size_t)DIM;

    const int c3 = cid[row] * 3;
    const float* wp0 = Wp + (size_t)c3 * POS;  // 3 consecutive rows of W_pos
    const float* wf0 = Wf + (size_t)c3 * LAT;  // 3 consecutive rows of W_feat

    float a0 = 0.f, a1 = 0.f, a2 = 0.f;

#pragma unroll
    for (int i = 0; i < 5; ++i) {
        const int k = lane + 64 * i;
        if (k < DIM) {
            // X streamed once: nontemporal to avoid evicting weights from L2.
            const float x = __builtin_nontemporal_load(xrow + k);
            float w0, w1, w2;
            if (k < POS) {
                w0 = wp0[k];
                w1 = wp0[k + POS];
                w2 = wp0[k + 2 * POS];
            } else {
                const int kk = k - POS;
                w0 = wf0[kk];
                w1 = wf0[kk + LAT];
                w2 = wf0[kk + 2 * LAT];
            }
            a0 = fmaf(x, w0, a0);
            a1 = fmaf(x, w1, a1);
            a2 = fmaf(x, w2, a2);
        }
    }

    // Wave-wide butterfly reduction (64 lanes).
#pragma unroll
    for (int off = 32; off > 0; off >>= 1) {
        a0 += __shfl_xor(a0, off, 64);
        a1 += __shfl_xor(a1, off, 64);
        a2 += __shfl_xor(a2, off, 64);
    }

    if (lane == 0) {
        float* o = out + row * 3;
        o[0] = a0;
        o[1] = a1;
        o[2] = a2;
    }
}

extern "C" void kernel_launch(void* const* d_in, const int* in_sizes, int n_in,
                              void* d_out, int out_size, void* d_ws, size_t ws_size,
                              hipStream_t stream) {
    const float* X   = (const float*)d_in[0];
    const int*   cid = (const int*)d_in[1];
    const float* Wp  = (const float*)d_in[2];
    const float* Wf  = (const float*)d_in[3];
    float* out = (float*)d_out;

    const int n = in_sizes[1];  // number of rows (= cluster_ids count)

    // One 64-lane wave per row; 4 waves per 256-thread block.
    const int blocks = (n + 3) / 4;
    lad_kernel<<<blocks, 256, 0, stream>>>(X, cid, Wp, Wf, out, n);
}

// Round 2
// 210.306 us; speedup vs baseline: 1.0312x; 1.0312x over previous
//
#include <hip/hip_runtime.h>

// LinearAutoDecoder: rgb[n,j] = dot(X[n,:63], W_pos[3c+j]) + dot(X[n,63:], W_feat[3c+j]),
// c = cluster_ids[n]. One 64-lane wave per row; cluster is wave-uniform so all
// loads are coalesced. Reduction done entirely on the VALU via DPP (no DS ops).

constexpr int POS = 63;
constexpr int LAT = 256;
constexpr int DIM = POS + LAT;  // 319

// One butterfly/scan step: x += dpp_move(x, CTRL), invalid lanes contribute 0.
template <int CTRL>
__device__ __forceinline__ float dpp_add_step(float x) {
    int s = __builtin_amdgcn_update_dpp(0, __float_as_int(x), CTRL,
                                        0xF, 0xF, /*bound_ctrl=*/true);
    return x + __int_as_float(s);
}

// Classic GCN wave64 sum: row_shr 1/2/4/8 (inclusive scan within each row of 16),
// then row_bcast15 + row_bcast31. Total lands in lane 63. Pure VALU.
__device__ __forceinline__ float wave_reduce_sum(float x) {
    x = dpp_add_step<0x111>(x);  // row_shr:1
    x = dpp_add_step<0x112>(x);  // row_shr:2
    x = dpp_add_step<0x114>(x);  // row_shr:4
    x = dpp_add_step<0x118>(x);  // row_shr:8
    x = dpp_add_step<0x142>(x);  // row_bcast15
    x = dpp_add_step<0x143>(x);  // row_bcast31
    return x;                    // valid in lane 63
}

__global__ __launch_bounds__(256) void lad_kernel(
    const float* __restrict__ X,
    const int*   __restrict__ cid,
    const float* __restrict__ Wp,   // [192, 63]
    const float* __restrict__ Wf,   // [192, 256]
    float*       __restrict__ out,  // [N, 3]
    int n)
{
    const int lane = threadIdx.x & 63;
    const int wave = (int)((blockIdx.x * blockDim.x + threadIdx.x) >> 6);
    if (wave >= n) return;

    const size_t row = (size_t)wave;
    const float* xrow = X + row * (size_t)DIM;
    const float* xf   = xrow + POS;

    const int c3 = cid[row] * 3;
    const float* wp0 = Wp + (size_t)c3 * POS;
    const float* wf0 = Wf + (size_t)c3 * LAT;

    float a0 = 0.f, a1 = 0.f, a2 = 0.f;

    // Latent part: 256 = 4*64 features, no masking, fully coalesced.
#pragma unroll
    for (int i = 0; i < 4; ++i) {
        const int k = lane + 64 * i;
        const float x = __builtin_nontemporal_load(xf + k);  // streamed once
        a0 = fmaf(x, wf0[k], a0);
        a1 = fmaf(x, wf0[k + LAT], a1);
        a2 = fmaf(x, wf0[k + 2 * LAT], a2);
    }

    // Pos part: 63 features, exec-masked (keeps all loads in bounds).
    if (lane < POS) {
        const float x = __builtin_nontemporal_load(xrow + lane);
        a0 = fmaf(x, wp0[lane], a0);
        a1 = fmaf(x, wp0[lane + POS], a1);
        a2 = fmaf(x, wp0[lane + 2 * POS], a2);
    }

    a0 = wave_reduce_sum(a0);
    a1 = wave_reduce_sum(a1);
    a2 = wave_reduce_sum(a2);

    if (lane == 63) {
        float* o = out + row * 3;
        o[0] = a0;
        o[1] = a1;
        o[2] = a2;
    }
}

extern "C" void kernel_launch(void* const* d_in, const int* in_sizes, int n_in,
                              void* d_out, int out_size, void* d_ws, size_t ws_size,
                              hipStream_t stream) {
    const float* X   = (const float*)d_in[0];
    const int*   cid = (const int*)d_in[1];
    const float* Wp  = (const float*)d_in[2];
    const float* Wf  = (const float*)d_in[3];
    float* out = (float*)d_out;

    const int n = in_sizes[1];  // rows = cluster_ids count

    const int blocks = (n + 3) / 4;  // 4 waves per 256-thread block
    lad_kernel<<<blocks, 256, 0, stream>>>(X, cid, Wp, Wf, out, n);
}